// Round 15
// baseline (3176.928 us; speedup 1.0000x reference)
//
#include <hip/hip_runtime.h>

#define S_LEN 2048
#define DIN   50
#define H     64
#define XSTR  (S_LEN * DIN)

// tanh(v) = 1 - 2/(exp(2v)+1); ~1e-6 rel err, exact at +/-inf
__device__ __forceinline__ float tanh_fast(float v) {
    float e = __builtin_amdgcn_exp2f(v * 2.885390082f);   // exp(2v)
    return 1.0f - 2.0f * __builtin_amdgcn_rcpf(e + 1.0f);
}

__global__ __launch_bounds__(64)
__attribute__((amdgpu_waves_per_eu(1, 1)))   // 1 wave/SIMD: max register budget (R14: >88 confirmed)
void rnn_sw(const float* __restrict__ x,
            const float* __restrict__ W_ih0, const float* __restrict__ W_hh0,
            const float* __restrict__ b_ih0, const float* __restrict__ b_hh0,
            const float* __restrict__ W_ih1, const float* __restrict__ W_hh1,
            const float* __restrict__ b_ih1, const float* __restrict__ b_hh1,
            const float* __restrict__ W1, const float* __restrict__ b1,
            const float* __restrict__ W2, const float* __restrict__ b2,
            float* __restrict__ out)
{
    const int b    = blockIdx.x;         // one batch row per block (one wave)
    const int lane = threadIdx.x & 63;   // lane = output unit u for h1 AND h2

    __shared__ __align__(16) float h1s[H];      // h1[t]
    __shared__ __align__(16) float h2s[H];      // h2[t-1]
    __shared__ __align__(16) float xs[4][52];   // x-row ring (50 + 2 zero-pad)

    // ---- full weight rows per lane: 244 floats, statically indexed ----
    float whh0r[H], wih1r[H], whh1r[H];
    #pragma unroll
    for (int i = 0; i < H; ++i) {
        whh0r[i] = W_hh0[lane * H + i];
        wih1r[i] = W_ih1[lane * H + i];
        whh1r[i] = W_hh1[lane * H + i];
    }
    float wxr[52];
    #pragma unroll
    for (int i = 0; i < 52; ++i)
        wxr[i] = (i < DIN) ? W_ih0[lane * DIN + i] : 0.0f;
    const float b0  = b_ih0[lane] + b_hh0[lane];
    const float b1v = b_ih1[lane] + b_hh1[lane];

    const float* __restrict__ xrow = x + (size_t)b * (size_t)XSTR;

    // ---- stage x[0..3]; prefetch x[4], x[5] into registers ----
    if (lane < 52) {
        #pragma unroll
        for (int r = 0; r < 4; ++r)
            xs[r][lane] = (lane < DIN) ? xrow[r * DIN + lane] : 0.0f;
    }
    float xldA = (lane < DIN) ? xrow[4 * DIN + lane] : 0.0f;   // x[t+4] at t=0
    float xldB = (lane < DIN) ? xrow[5 * DIN + lane] : 0.0f;   // x[t+5] at t=0

    h2s[lane] = 0.0f;                    // h2[-1]

    // ---- prologue: h1[0] = tanh(W_ih0 . x[0] + b0)  (same-wave DS ordering) ----
    {
        float a0 = b0, a1 = 0.0f, a2 = 0.0f, a3 = 0.0f;
        #pragma unroll
        for (int q = 0; q < 13; ++q) {
            float4 xv = *(const float4*)&xs[0][4 * q];
            a0 = fmaf(xv.x, wxr[4 * q + 0], a0);
            a1 = fmaf(xv.y, wxr[4 * q + 1], a1);
            a2 = fmaf(xv.z, wxr[4 * q + 2], a2);
            a3 = fmaf(xv.w, wxr[4 * q + 3], a3);
        }
        h1s[lane] = tanh_fast((a0 + a1) + (a2 + a3));
    }

    // ---- steady state: interval t computes h2[t] and h1[t+1] from {h1[t], h2[t-1], x[t+1]}.
    //      Zero barriers: single wave, DS ops execute in order. ----
    for (int t = 0; t < S_LEN; ++t) {
        const float* xsl = &xs[(t + 1) & 3][0];

        float a0 = 0, a1 = 0, a2 = 0, a3 = 0;    // Whh0 . h1[t]
        float i0 = 0, i1 = 0, i2 = 0, i3 = 0;    // Wih1 . h1[t]
        float c0 = 0, c1 = 0, c2 = 0, c3 = 0;    // Whh1 . h2[t-1]
        #pragma unroll
        for (int q = 0; q < 16; ++q) {           // h1 read once, feeds 2 matmuls
            float4 hv = *(const float4*)&h1s[4 * q];
            a0 = fmaf(hv.x, whh0r[4 * q + 0], a0);
            a1 = fmaf(hv.y, whh0r[4 * q + 1], a1);
            a2 = fmaf(hv.z, whh0r[4 * q + 2], a2);
            a3 = fmaf(hv.w, whh0r[4 * q + 3], a3);
            i0 = fmaf(hv.x, wih1r[4 * q + 0], i0);
            i1 = fmaf(hv.y, wih1r[4 * q + 1], i1);
            i2 = fmaf(hv.z, wih1r[4 * q + 2], i2);
            i3 = fmaf(hv.w, wih1r[4 * q + 3], i3);
        }
        #pragma unroll
        for (int q = 0; q < 16; ++q) {
            float4 hv = *(const float4*)&h2s[4 * q];
            c0 = fmaf(hv.x, whh1r[4 * q + 0], c0);
            c1 = fmaf(hv.y, whh1r[4 * q + 1], c1);
            c2 = fmaf(hv.z, whh1r[4 * q + 2], c2);
            c3 = fmaf(hv.w, whh1r[4 * q + 3], c3);
        }
        float x0 = 0, x1 = 0, x2 = 0, x3 = 0;    // W_ih0 . x[t+1]
        #pragma unroll
        for (int q = 0; q < 13; ++q) {
            float4 xv = *(const float4*)&xsl[4 * q];
            x0 = fmaf(xv.x, wxr[4 * q + 0], x0);
            x1 = fmaf(xv.y, wxr[4 * q + 1], x1);
            x2 = fmaf(xv.z, wxr[4 * q + 2], x2);
            x3 = fmaf(xv.w, wxr[4 * q + 3], x3);
        }

        float h1n = tanh_fast((((a0 + a1) + (a2 + a3)) + ((x0 + x1) + (x2 + x3))) + b0);
        float h2n = tanh_fast((((i0 + i1) + (i2 + i3)) + ((c0 + c1) + (c2 + c3))) + b1v);

        // writes after all reads (program order); next iter's reads see them (in-order DS)
        h1s[lane] = h1n;                         // h1[t+1]
        h2s[lane] = h2n;                         // h2[t]

        // x ring: publish x[t+4] into the slot of dead x[t]; rotate prefetch regs.
        if (lane < 52) xs[t & 3][lane] = xldA;
        xldA = xldB;
        const int tn = (t + 6 < S_LEN) ? (t + 6) : (S_LEN - 1);   // clamped: tail values unused
        xldB = (lane < DIN) ? xrow[(size_t)tn * DIN + lane] : 0.0f;
    }
    // (interval 2047 also writes h1[2048] from clamped x — value never read)

    // ---- head: relu(h2[2047] @ W1^T + b1) -> sigmoid(. @ W2^T + b2) ----
    {
        float hv = 0.0f;
        if (lane < 32) {
            float acc = b1[lane];
            #pragma unroll
            for (int k = 0; k < H; ++k)
                acc = fmaf(h2s[k], W1[lane * H + k], acc);
            hv = fmaxf(acc, 0.0f) * W2[lane];
        }
        #pragma unroll
        for (int off = 32; off; off >>= 1)
            hv += __shfl_xor(hv, off, 64);
        if (lane == 0)
            out[b] = 1.0f / (1.0f + __expf(-(hv + b2[0])));
    }
}

extern "C" void kernel_launch(void* const* d_in, const int* in_sizes, int n_in,
                              void* d_out, int out_size, void* d_ws, size_t ws_size,
                              hipStream_t stream) {
    const float* x     = (const float*)d_in[0];
    const float* W_ih0 = (const float*)d_in[1];
    const float* W_hh0 = (const float*)d_in[2];
    const float* b_ih0 = (const float*)d_in[3];
    const float* b_hh0 = (const float*)d_in[4];
    const float* W_ih1 = (const float*)d_in[5];
    const float* W_hh1 = (const float*)d_in[6];
    const float* b_ih1 = (const float*)d_in[7];
    const float* b_hh1 = (const float*)d_in[8];
    const float* W1    = (const float*)d_in[9];
    const float* b1    = (const float*)d_in[10];
    const float* W2    = (const float*)d_in[11];
    const float* b2    = (const float*)d_in[12];
    float* out = (float*)d_out;

    rnn_sw<<<dim3(512), dim3(64), 0, stream>>>(
        x, W_ih0, W_hh0, b_ih0, b_hh0,
        W_ih1, W_hh1, b_ih1, b_hh1,
        W1, b1, W2, b2, out);
}